// Round 1
// baseline (585.543 us; speedup 1.0000x reference)
//
#include <hip/hip_runtime.h>

typedef __attribute__((ext_vector_type(8))) short short8;
typedef __attribute__((ext_vector_type(4))) float f32x4;
typedef unsigned short u16;

#define MFMA_BF16(a, b, c) __builtin_amdgcn_mfma_f32_16x16x32_bf16((a), (b), (c), 0, 0, 0)

constexpr int D = 1024;
constexpr int L = 2048;
constexpr int NHEAD = 16;
constexpr int HD = 64;

__device__ __forceinline__ u16 f2bf(float f) {
  unsigned u = __builtin_bit_cast(unsigned, f);
  u = (u + 0x7fffu + ((u >> 16) & 1u)) >> 16;
  return (u16)u;
}

__device__ __forceinline__ short8 cvt8(f32x4 lo, f32x4 hi) {
  short8 r;
  r[0] = (short)f2bf(lo[0]); r[1] = (short)f2bf(lo[1]);
  r[2] = (short)f2bf(lo[2]); r[3] = (short)f2bf(lo[3]);
  r[4] = (short)f2bf(hi[0]); r[5] = (short)f2bf(hi[1]);
  r[6] = (short)f2bf(hi[2]); r[7] = (short)f2bf(hi[3]);
  return r;
}

// ---------- weight transpose + convert: W[k][n] f32 -> WT[n][k] bf16 ----------
__global__ __launch_bounds__(256) void wt_trans_kernel(const float* W0, const float* W1,
                                                       const float* W2, const float* W3,
                                                       u16* out) {
  const float* W = blockIdx.z == 0 ? W0 : blockIdx.z == 1 ? W1 : blockIdx.z == 2 ? W2 : W3;
  u16* o = out + (size_t)blockIdx.z * D * D;
  __shared__ float t[32][33];
  int x = threadIdx.x & 31, y = threadIdx.x >> 5;
  int k0 = blockIdx.x * 32, n0 = blockIdx.y * 32;
#pragma unroll
  for (int i = 0; i < 4; i++) {
    int ky = y * 4 + i;
    t[ky][x] = W[(size_t)(k0 + ky) * D + n0 + x];
  }
  __syncthreads();
#pragma unroll
  for (int i = 0; i < 4; i++) {
    int ny = y * 4 + i;
    o[(size_t)(n0 + ny) * D + k0 + x] = f2bf(t[x][ny]);
  }
}

// ---------- RoPE tables: cos/sin[l][i], angle = l * 10000^(-i/32) ----------
__global__ __launch_bounds__(256) void rope_tab_kernel(float* ct, float* st) {
  int t = blockIdx.x * 256 + threadIdx.x;  // L*32 = 65536
  int i = t & 31, pos = t >> 5;
  float invf = powf(10000.0f, -(float)i / 32.0f);
  float ang = (float)pos * invf;
  ct[t] = cosf(ang);
  st[t] = sinf(ang);
}

// ---------- fused QKV projection GEMM + bias + RoPE epilogue ----------
// A = X[4096][1024] f32, B = WT[n][k] bf16. Tile: 128(M) x 64(N), 4 waves.
// z=0: q out [B,H,L,hd] (roped); z=1: k out (roped); z=2: v out transposed [B,H,hd,L].
__global__ __launch_bounds__(256) void proj_gemm_kernel(
    const float* Q, const float* K, const float* V, const u16* wT,
    const float* bq, const float* bk, const float* bv,
    const float* ct, const float* st,
    u16* qo, u16* ko, u16* vT) {
  int z = blockIdx.z;
  const float* A = z == 0 ? Q : z == 1 ? K : V;
  const u16* W = wT + (size_t)z * D * D;
  const float* bias = z == 0 ? bq : z == 1 ? bk : bv;

  int w = threadIdx.x >> 6, lane = threadIdx.x & 63;
  int r = lane & 15, c = lane >> 4;
  int m0 = blockIdx.y * 128 + w * 32;
  int n0 = blockIdx.x * 64;

  const float* a0 = A + (size_t)(m0 + r) * D + c * 8;
  const u16* b0 = W + (size_t)(n0 + r) * D + c * 8;

  f32x4 acc[2][4];
#pragma unroll
  for (int mi = 0; mi < 2; mi++)
#pragma unroll
    for (int ni = 0; ni < 4; ni++) acc[mi][ni] = f32x4{0.f, 0.f, 0.f, 0.f};

  for (int kk = 0; kk < D; kk += 32) {
    short8 af[2];
#pragma unroll
    for (int mi = 0; mi < 2; mi++) {
      const float* ap = a0 + (size_t)mi * 16 * D;
      f32x4 lo = *(const f32x4*)(ap);
      f32x4 hi = *(const f32x4*)(ap + 4);
      af[mi] = cvt8(lo, hi);
    }
    short8 bf8[4];
#pragma unroll
    for (int ni = 0; ni < 4; ni++)
      bf8[ni] = *(const short8*)(b0 + (size_t)ni * 16 * D);
#pragma unroll
    for (int mi = 0; mi < 2; mi++)
#pragma unroll
      for (int ni = 0; ni < 4; ni++)
        acc[mi][ni] = MFMA_BF16(af[mi], bf8[ni], acc[mi][ni]);
    a0 += 32;
    b0 += 32;
  }

  int h = n0 >> 6;  // BN=64 == head_dim, one head per block column
#pragma unroll
  for (int mi = 0; mi < 2; mi++) {
#pragma unroll
    for (int j = 0; j < 4; j++) {
      int grow = m0 + mi * 16 + c * 4 + j;  // 0..4095
      int b = grow >> 11, ll = grow & 2047;
      if (z < 2) {
        u16* o = (z == 0) ? qo : ko;
        size_t dst = ((size_t)(b * NHEAD + h) * L + ll) * HD;
#pragma unroll
        for (int ni = 0; ni < 2; ni++) {
          int d = ni * 16 + r;  // 0..31
          float x1 = acc[mi][ni][j] + bias[n0 + d];
          float x2 = acc[mi][ni + 2][j] + bias[n0 + 32 + d];
          float cs = ct[ll * 32 + d], sn = st[ll * 32 + d];
          o[dst + d]      = f2bf(x1 * cs - x2 * sn);
          o[dst + d + 32] = f2bf(x2 * cs + x1 * sn);
        }
      } else {
#pragma unroll
        for (int ni = 0; ni < 4; ni++) {
          int d = ni * 16 + r;
          float val = acc[mi][ni][j] + bias[n0 + d];
          vT[((size_t)(b * NHEAD + h) * HD + d) * L + ll] = f2bf(val);
        }
      }
    }
  }
}

// ---------- causal flash attention ----------
// grid: x = q-tile (L/64), y = b*NHEAD+h. 4 waves x 16 q-rows. 32-key blocks.
__global__ __launch_bounds__(256) void attn_kernel(const u16* q, const u16* k,
                                                   const u16* vT, u16* O) {
  int bh = blockIdx.y;
  int qt = blockIdx.x;
  int w = threadIdx.x >> 6, lane = threadIdx.x & 63;
  int r = lane & 15, c = lane >> 4;
  int qb = qt * 64 + w * 16;

  const u16* qp = q + ((size_t)bh * L + qb) * HD;
  const u16* kp = k + (size_t)bh * L * HD;
  const u16* vp = vT + (size_t)bh * HD * L;

  __shared__ __align__(16) u16 plds[4][16][40];  // padded stride 40 (80B)

  short8 aq0 = *(const short8*)(qp + r * HD + c * 8);
  short8 aq1 = *(const short8*)(qp + r * HD + 32 + c * 8);

  f32x4 o[4];
  float m[4], s[4];
#pragma unroll
  for (int n = 0; n < 4; n++) o[n] = f32x4{0.f, 0.f, 0.f, 0.f};
#pragma unroll
  for (int j = 0; j < 4; j++) { m[j] = -3.0e38f; s[j] = 0.f; }

  int nkb = ((qb + 15) >> 5) + 1;
  for (int kb = 0; kb < nkb; kb++) {
    int kbase = kb * 32;
    const u16* krow = kp + (size_t)(kbase + r) * HD + c * 8;
    short8 bk00 = *(const short8*)(krow);
    short8 bk01 = *(const short8*)(krow + 32);
    short8 bk10 = *(const short8*)(krow + 16 * HD);
    short8 bk11 = *(const short8*)(krow + 16 * HD + 32);
    f32x4 S0 = f32x4{0.f, 0.f, 0.f, 0.f}, S1 = f32x4{0.f, 0.f, 0.f, 0.f};
    S0 = MFMA_BF16(aq0, bk00, S0);
    S0 = MFMA_BF16(aq1, bk01, S0);
    S1 = MFMA_BF16(aq0, bk10, S1);
    S1 = MFMA_BF16(aq1, bk11, S1);

    bool edge = (kbase + 31) > qb;
#pragma unroll
    for (int j = 0; j < 4; j++) {
      float s0 = S0[j] * 0.125f, s1 = S1[j] * 0.125f;
      if (edge) {
        int qrow = qb + c * 4 + j;
        if (kbase + r > qrow) s0 = -3.0e38f;
        if (kbase + 16 + r > qrow) s1 = -3.0e38f;
      }
      float mx = fmaxf(s0, s1);
      mx = fmaxf(mx, __shfl_xor(mx, 1));
      mx = fmaxf(mx, __shfl_xor(mx, 2));
      mx = fmaxf(mx, __shfl_xor(mx, 4));
      mx = fmaxf(mx, __shfl_xor(mx, 8));
      float mn = fmaxf(m[j], mx);
      float alpha = __expf(m[j] - mn);
      m[j] = mn;
      float p0 = __expf(s0 - mn), p1 = __expf(s1 - mn);
      float rs = p0 + p1;
      rs += __shfl_xor(rs, 1);
      rs += __shfl_xor(rs, 2);
      rs += __shfl_xor(rs, 4);
      rs += __shfl_xor(rs, 8);
      s[j] = s[j] * alpha + rs;
      o[0][j] *= alpha;
      o[1][j] *= alpha;
      o[2][j] *= alpha;
      o[3][j] *= alpha;
      plds[w][c * 4 + j][r] = f2bf(p0);
      plds[w][c * 4 + j][16 + r] = f2bf(p1);
    }
    short8 pa = *(const short8*)&plds[w][r][c * 8];
#pragma unroll
    for (int n = 0; n < 4; n++) {
      short8 bv8 = *(const short8*)(vp + (size_t)(n * 16 + r) * L + kbase + c * 8);
      o[n] = MFMA_BF16(pa, bv8, o[n]);
    }
  }

  int b = bh >> 4, h = bh & 15;
#pragma unroll
  for (int n = 0; n < 4; n++) {
#pragma unroll
    for (int j = 0; j < 4; j++) {
      int qrow = qb + c * 4 + j;
      float val = o[n][j] / s[j];
      O[((size_t)(b * L + qrow)) * D + h * HD + n * 16 + r] = f2bf(val);
    }
  }
}

// ---------- output projection: out = O @ Wo^T(+bo), f32 out ----------
__global__ __launch_bounds__(256) void oproj_gemm_kernel(const u16* A, const u16* wT,
                                                         const float* bias, float* out) {
  int w = threadIdx.x >> 6, lane = threadIdx.x & 63;
  int r = lane & 15, c = lane >> 4;
  int m0 = blockIdx.y * 128 + w * 32;
  int n0 = blockIdx.x * 64;

  const u16* a0 = A + (size_t)(m0 + r) * D + c * 8;
  const u16* b0 = wT + (size_t)(n0 + r) * D + c * 8;

  f32x4 acc[2][4];
#pragma unroll
  for (int mi = 0; mi < 2; mi++)
#pragma unroll
    for (int ni = 0; ni < 4; ni++) acc[mi][ni] = f32x4{0.f, 0.f, 0.f, 0.f};

  for (int kk = 0; kk < D; kk += 32) {
    short8 af[2];
    af[0] = *(const short8*)(a0);
    af[1] = *(const short8*)(a0 + (size_t)16 * D);
    short8 bf8[4];
#pragma unroll
    for (int ni = 0; ni < 4; ni++)
      bf8[ni] = *(const short8*)(b0 + (size_t)ni * 16 * D);
#pragma unroll
    for (int mi = 0; mi < 2; mi++)
#pragma unroll
      for (int ni = 0; ni < 4; ni++)
        acc[mi][ni] = MFMA_BF16(af[mi], bf8[ni], acc[mi][ni]);
    a0 += 32;
    b0 += 32;
  }

#pragma unroll
  for (int mi = 0; mi < 2; mi++)
#pragma unroll
    for (int j = 0; j < 4; j++) {
      int grow = m0 + mi * 16 + c * 4 + j;
#pragma unroll
      for (int ni = 0; ni < 4; ni++) {
        int gcol = n0 + ni * 16 + r;
        out[(size_t)grow * D + gcol] = acc[mi][ni][j] + bias[gcol];
      }
    }
}

extern "C" void kernel_launch(void* const* d_in, const int* in_sizes, int n_in,
                              void* d_out, int out_size, void* d_ws, size_t ws_size,
                              hipStream_t stream) {
  const float* Q = (const float*)d_in[0];
  const float* K = (const float*)d_in[1];
  const float* V = (const float*)d_in[2];
  const float* Wq = (const float*)d_in[3];
  const float* Wk = (const float*)d_in[4];
  const float* Wv = (const float*)d_in[5];
  const float* Wv_o = (const float*)d_in[6];
  const float* bq = (const float*)d_in[7];
  const float* bk = (const float*)d_in[8];
  const float* bv = (const float*)d_in[9];
  const float* bo = (const float*)d_in[10];
  float* out = (float*)d_out;

  char* ws = (char*)d_ws;
  // layout (bytes):
  //   0        : wT  4 x 1024x1024 bf16 (q,k,v,o transposed weights) = 8,388,608
  //   8388608  : cos table 65536 f32 = 262144
  //   8650752  : sin table 65536 f32 = 262144
  //   8912896  : q   [B,H,L,hd] bf16 = 8,388,608
  //   17301504 : k   [B,H,L,hd] bf16 = 8,388,608
  //   25690112 : vT  [B,H,hd,L] bf16 = 8,388,608
  //   34078720 : O   [B,L,D]    bf16 = 8,388,608   (total 42,467,328)
  u16* wT = (u16*)(ws);
  u16* woT = wT + (size_t)3 * 1024 * 1024;
  float* ct = (float*)(ws + 8388608);
  float* st = (float*)(ws + 8650752);
  u16* qbuf = (u16*)(ws + 8912896);
  u16* kbuf = (u16*)(ws + 17301504);
  u16* vbuf = (u16*)(ws + 25690112);
  u16* obuf = (u16*)(ws + 34078720);

  wt_trans_kernel<<<dim3(32, 32, 4), 256, 0, stream>>>(Wq, Wk, Wv, Wv_o, wT);
  rope_tab_kernel<<<dim3(256), 256, 0, stream>>>(ct, st);
  proj_gemm_kernel<<<dim3(16, 32, 3), 256, 0, stream>>>(Q, K, V, wT, bq, bk, bv, ct, st,
                                                        qbuf, kbuf, vbuf);
  attn_kernel<<<dim3(32, 32), 256, 0, stream>>>(qbuf, kbuf, vbuf, obuf);
  oproj_gemm_kernel<<<dim3(16, 32), 256, 0, stream>>>(obuf, woT, bo, out);
}

// Round 2
// 420.001 us; speedup vs baseline: 1.3941x; 1.3941x over previous
//
#include <hip/hip_runtime.h>

typedef __attribute__((ext_vector_type(8))) short short8;
typedef __attribute__((ext_vector_type(4))) float f32x4;
typedef unsigned short u16;
typedef unsigned int u32;

#define MFMA_BF16(a, b, c) __builtin_amdgcn_mfma_f32_16x16x32_bf16((a), (b), (c), 0, 0, 0)

constexpr int D = 1024;
constexpr int L = 2048;
constexpr int NHEAD = 16;
constexpr int HD = 64;

__device__ __forceinline__ u16 f2bf(float f) {
  unsigned u = __builtin_bit_cast(unsigned, f);
  u = (u + 0x7fffu + ((u >> 16) & 1u)) >> 16;
  return (u16)u;
}

__device__ __forceinline__ short8 cvt8(f32x4 lo, f32x4 hi) {
  short8 r;
  r[0] = (short)f2bf(lo[0]); r[1] = (short)f2bf(lo[1]);
  r[2] = (short)f2bf(lo[2]); r[3] = (short)f2bf(lo[3]);
  r[4] = (short)f2bf(hi[0]); r[5] = (short)f2bf(hi[1]);
  r[6] = (short)f2bf(hi[2]); r[7] = (short)f2bf(hi[3]);
  return r;
}

// async global->LDS, 16B per lane. dst must be wave-uniform; per-lane global src.
__device__ __forceinline__ void gload16(const u16* src, u16* dst) {
  __builtin_amdgcn_global_load_lds(
      (const __attribute__((address_space(1))) u32*)(src),
      (__attribute__((address_space(3))) u32*)(dst), 16, 0, 0);
}

// ---------- weight transpose + convert: W[k][n] f32 -> WT[n][k] bf16 ----------
__global__ __launch_bounds__(256) void wt_trans_kernel(const float* W0, const float* W1,
                                                       const float* W2, const float* W3,
                                                       u16* out) {
  const float* W = blockIdx.z == 0 ? W0 : blockIdx.z == 1 ? W1 : blockIdx.z == 2 ? W2 : W3;
  u16* o = out + (size_t)blockIdx.z * D * D;
  __shared__ float t[32][33];
  int x = threadIdx.x & 31, y = threadIdx.x >> 5;
  int k0 = blockIdx.x * 32, n0 = blockIdx.y * 32;
#pragma unroll
  for (int i = 0; i < 4; i++) {
    int ky = y * 4 + i;
    t[ky][x] = W[(size_t)(k0 + ky) * D + n0 + x];
  }
  __syncthreads();
#pragma unroll
  for (int i = 0; i < 4; i++) {
    int ny = y * 4 + i;
    o[(size_t)(n0 + ny) * D + k0 + x] = f2bf(t[x][ny]);
  }
}

// ---------- RoPE tables ----------
__global__ __launch_bounds__(256) void rope_tab_kernel(float* ct, float* st) {
  int t = blockIdx.x * 256 + threadIdx.x;  // L*32 = 65536
  int i = t & 31, pos = t >> 5;
  float invf = powf(10000.0f, -(float)i / 32.0f);
  float ang = (float)pos * invf;
  ct[t] = cosf(ang);
  st[t] = sinf(ang);
}

// ---------- convert X (Q,K,V inputs) f32 -> bf16 ----------
__global__ __launch_bounds__(256) void cvt_x_kernel(const float* Q, const float* K,
                                                    const float* V, u16* xb) {
  const float* src = blockIdx.y == 0 ? Q : blockIdx.y == 1 ? K : V;
  u16* dst = xb + (size_t)blockIdx.y * 4096 * D;
  int t = blockIdx.x * 256 + threadIdx.x;  // 524288 threads, 8 elems each
  const float* p = src + (size_t)t * 8;
  f32x4 lo = *(const f32x4*)p;
  f32x4 hi = *(const f32x4*)(p + 4);
  *(short8*)(dst + (size_t)t * 8) = cvt8(lo, hi);
}

// ---------- fused QKV projection GEMM + bias + RoPE epilogue (128x128 tile) ----------
template <bool BF16A>
__global__ __launch_bounds__(256) void proj_gemm_kernel(
    const float* Qf, const float* Kf, const float* Vf, const u16* xb, const u16* wT,
    const float* bq, const float* bk, const float* bv,
    const float* ct, const float* st,
    u16* qo, u16* ko, u16* vT) {
  int i = blockIdx.x;                  // 768 blocks, XCD-swizzled (bijective: 768%8==0)
  int swz = (i & 7) * 96 + (i >> 3);
  int z = swz >> 8;
  int bx = swz & 7;
  int by = (swz >> 3) & 31;

  const u16* W = wT + (size_t)z * D * D;
  const float* bias = z == 0 ? bq : z == 1 ? bk : bv;

  int w = threadIdx.x >> 6, lane = threadIdx.x & 63;
  int r = lane & 15, c = lane >> 4;
  int wr = w >> 1, wc = w & 1;
  int m0 = by * 128 + wr * 64;
  int n0 = bx * 128 + wc * 64;

  const u16* a0b = nullptr;
  const float* a0f = nullptr;
  if constexpr (BF16A) {
    a0b = xb + (size_t)z * 4096 * D + (size_t)(m0 + r) * D + c * 8;
  } else {
    const float* Af = z == 0 ? Qf : z == 1 ? Kf : Vf;
    a0f = Af + (size_t)(m0 + r) * D + c * 8;
  }
  const u16* b0 = W + (size_t)(n0 + r) * D + c * 8;

  f32x4 acc[4][4];
#pragma unroll
  for (int mi = 0; mi < 4; mi++)
#pragma unroll
    for (int ni = 0; ni < 4; ni++) acc[mi][ni] = f32x4{0.f, 0.f, 0.f, 0.f};

  for (int kk = 0; kk < D; kk += 32) {
    short8 af[4], bf[4];
#pragma unroll
    for (int mi = 0; mi < 4; mi++) {
      if constexpr (BF16A) {
        af[mi] = *(const short8*)(a0b + (size_t)mi * 16 * D);
      } else {
        const float* ap = a0f + (size_t)mi * 16 * D;
        af[mi] = cvt8(*(const f32x4*)ap, *(const f32x4*)(ap + 4));
      }
    }
#pragma unroll
    for (int ni = 0; ni < 4; ni++) bf[ni] = *(const short8*)(b0 + (size_t)ni * 16 * D);
#pragma unroll
    for (int mi = 0; mi < 4; mi++)
#pragma unroll
      for (int ni = 0; ni < 4; ni++)
        acc[mi][ni] = MFMA_BF16(af[mi], bf[ni], acc[mi][ni]);
    if constexpr (BF16A) a0b += 32; else a0f += 32;
    b0 += 32;
  }

  int h = n0 >> 6;
#pragma unroll
  for (int mi = 0; mi < 4; mi++) {
#pragma unroll
    for (int j = 0; j < 4; j++) {
      int grow = m0 + mi * 16 + c * 4 + j;
      int b = grow >> 11, ll = grow & 2047;
      if (z < 2) {
        u16* o = (z == 0) ? qo : ko;
        size_t dst = ((size_t)(b * NHEAD + h) * L + ll) * HD;
#pragma unroll
        for (int ni = 0; ni < 2; ni++) {
          int d = ni * 16 + r;  // 0..31
          float x1 = acc[mi][ni][j] + bias[n0 + d];
          float x2 = acc[mi][ni + 2][j] + bias[n0 + 32 + d];
          float cs = ct[ll * 32 + d], sn = st[ll * 32 + d];
          o[dst + d]      = f2bf(x1 * cs - x2 * sn);
          o[dst + d + 32] = f2bf(x2 * cs + x1 * sn);
        }
      } else {
#pragma unroll
        for (int ni = 0; ni < 4; ni++) {
          int d = ni * 16 + r;
          float val = acc[mi][ni][j] + bias[n0 + d];
          vT[((size_t)(b * NHEAD + h) * HD + d) * L + ll] = f2bf(val);
        }
      }
    }
  }
}

// ---------- causal flash attention, KVBLK=64, LDS-staged K/V (2-phase dbuf) ----------
// grid: 1024 blocks XCD-swizzled; within XCD chunk: per-head, q-tiles heavy-first.
__global__ __launch_bounds__(256) void attn_kernel(const u16* qg, const u16* kg,
                                                   const u16* vg, u16* O) {
  int i = blockIdx.x;
  int sw = (i & 7) * 128 + (i >> 3);  // bijective, 1024%8==0
  int bh = sw >> 5;
  int qt = 31 - (sw & 31);  // heavy tiles first

  int w = threadIdx.x >> 6, lane = threadIdx.x & 63;
  int r = lane & 15, c = lane >> 4;
  int qb = qt * 64 + w * 16;

  const u16* qp = qg + ((size_t)bh * L + qb) * HD;
  const u16* kp = kg + (size_t)bh * L * HD;
  const u16* vp = vg + (size_t)bh * HD * L;

  // 40960 B total -> 4 blocks/CU
  __shared__ __align__(16) u16 kls[2][4096];        // [64 keys][64 d], chunk-XOR-swizzled
  __shared__ __align__(16) u16 vls[2][4096];        // [64 d][64 keys], chunk-XOR-swizzled
  __shared__ __align__(16) u16 plds[4][16][64];     // per-wave P, element-XOR-swizzled

  short8 aq0 = *(const short8*)(qp + r * HD + c * 8);
  short8 aq1 = *(const short8*)(qp + r * HD + 32 + c * 8);

  f32x4 o[4];
  float m[4], s[4];
#pragma unroll
  for (int n = 0; n < 4; n++) o[n] = f32x4{0.f, 0.f, 0.f, 0.f};
#pragma unroll
  for (int j = 0; j < 4; j++) { m[j] = -3.0e38f; s[j] = 0.f; }

  int nkt = qt + 1;

  // prologue: stage tile 0 (wave w stages chunks [(rd*4+w)*64, +64) of each tensor)
#pragma unroll
  for (int rd = 0; rd < 2; rd++) {
    int q0 = (rd * 4 + w) << 6;
    int qq = q0 + lane;
    int row = qq >> 3;
    int gch = (qq & 7) ^ (row & 7);  // pre-swizzled source (rule 21)
    gload16(kp + (size_t)row * HD + gch * 8, &kls[0][q0 * 8]);
    gload16(vp + (size_t)row * L + gch * 8, &vls[0][q0 * 8]);
  }

  for (int kt = 0; kt < nkt; kt++) {
    int cur = kt & 1;
    __syncthreads();  // drains vmcnt (stage of buf[cur] complete) + barrier
    if (kt + 1 < nkt) {
      int kb2 = (kt + 1) * 64;
      const u16* kp2 = kp + (size_t)kb2 * HD;
      const u16* vp2 = vp + kb2;
#pragma unroll
      for (int rd = 0; rd < 2; rd++) {
        int q0 = (rd * 4 + w) << 6;
        int qq = q0 + lane;
        int row = qq >> 3;
        int gch = (qq & 7) ^ (row & 7);
        gload16(kp2 + (size_t)row * HD + gch * 8, &kls[cur ^ 1][q0 * 8]);
        gload16(vp2 + (size_t)row * L + gch * 8, &vls[cur ^ 1][q0 * 8]);
      }
    }
    const u16* kb_ = kls[cur];
    const u16* vb_ = vls[cur];
    int kbase = kt * 64;

    // S = Q K^T for 64 keys
    f32x4 S[4];
#pragma unroll
    for (int ks = 0; ks < 4; ks++) {
      int row = ks * 16 + r;
      short8 kf0 = *(const short8*)(kb_ + row * 64 + ((c ^ (row & 7)) << 3));
      short8 kf1 = *(const short8*)(kb_ + row * 64 + (((4 + c) ^ (row & 7)) << 3));
      S[ks] = f32x4{0.f, 0.f, 0.f, 0.f};
      S[ks] = MFMA_BF16(aq0, kf0, S[ks]);
      S[ks] = MFMA_BF16(aq1, kf1, S[ks]);
    }

    bool edge = (kbase + 63) > qb;
#pragma unroll
    for (int j = 0; j < 4; j++) {
      float sv0 = S[0][j] * 0.125f, sv1 = S[1][j] * 0.125f;
      float sv2 = S[2][j] * 0.125f, sv3 = S[3][j] * 0.125f;
      if (edge) {
        int qrow = qb + c * 4 + j;
        if (kbase + r > qrow) sv0 = -3.0e38f;
        if (kbase + 16 + r > qrow) sv1 = -3.0e38f;
        if (kbase + 32 + r > qrow) sv2 = -3.0e38f;
        if (kbase + 48 + r > qrow) sv3 = -3.0e38f;
      }
      float mx = fmaxf(fmaxf(sv0, sv1), fmaxf(sv2, sv3));
      mx = fmaxf(mx, __shfl_xor(mx, 1));
      mx = fmaxf(mx, __shfl_xor(mx, 2));
      mx = fmaxf(mx, __shfl_xor(mx, 4));
      mx = fmaxf(mx, __shfl_xor(mx, 8));
      float mn = fmaxf(m[j], mx);
      float alpha = __expf(m[j] - mn);
      m[j] = mn;
      float p0 = __expf(sv0 - mn), p1 = __expf(sv1 - mn);
      float p2 = __expf(sv2 - mn), p3 = __expf(sv3 - mn);
      float rs = (p0 + p1) + (p2 + p3);
      rs += __shfl_xor(rs, 1);
      rs += __shfl_xor(rs, 2);
      rs += __shfl_xor(rs, 4);
      rs += __shfl_xor(rs, 8);
      s[j] = s[j] * alpha + rs;
      o[0][j] *= alpha;
      o[1][j] *= alpha;
      o[2][j] *= alpha;
      o[3][j] *= alpha;
      int prow = c * 4 + j, xr = (prow & 7) << 3;
      plds[w][prow][(r) ^ xr]      = f2bf(p0);
      plds[w][prow][(16 + r) ^ xr] = f2bf(p1);
      plds[w][prow][(32 + r) ^ xr] = f2bf(p2);
      plds[w][prow][(48 + r) ^ xr] = f2bf(p3);
    }

    int xrr = (r & 7) << 3;
    short8 pa0 = *(const short8*)&plds[w][r][(c * 8) ^ xrr];
    short8 pa1 = *(const short8*)&plds[w][r][(32 + c * 8) ^ xrr];
#pragma unroll
    for (int n = 0; n < 4; n++) {
      int row = n * 16 + r;
      short8 vf0 = *(const short8*)(vb_ + row * 64 + ((c ^ (row & 7)) << 3));
      short8 vf1 = *(const short8*)(vb_ + row * 64 + (((4 + c) ^ (row & 7)) << 3));
      o[n] = MFMA_BF16(pa0, vf0, o[n]);
      o[n] = MFMA_BF16(pa1, vf1, o[n]);
    }
  }

  int b = bh >> 4, h = bh & 15;
#pragma unroll
  for (int n = 0; n < 4; n++) {
#pragma unroll
    for (int j = 0; j < 4; j++) {
      int qrow = qb + c * 4 + j;
      float val = o[n][j] / s[j];
      O[((size_t)(b * L + qrow)) * D + h * HD + n * 16 + r] = f2bf(val);
    }
  }
}

// ---------- output projection (128x128 tile), f32 out + bias ----------
__global__ __launch_bounds__(256) void oproj_gemm_kernel(const u16* A, const u16* wT,
                                                         const float* bias, float* out) {
  int i = blockIdx.x;  // 256 blocks, XCD-swizzled
  int swz = (i & 7) * 32 + (i >> 3);
  int bx = swz & 7, by = swz >> 3;

  int w = threadIdx.x >> 6, lane = threadIdx.x & 63;
  int r = lane & 15, c = lane >> 4;
  int wr = w >> 1, wc = w & 1;
  int m0 = by * 128 + wr * 64;
  int n0 = bx * 128 + wc * 64;

  const u16* a0 = A + (size_t)(m0 + r) * D + c * 8;
  const u16* b0 = wT + (size_t)(n0 + r) * D + c * 8;

  f32x4 acc[4][4];
#pragma unroll
  for (int mi = 0; mi < 4; mi++)
#pragma unroll
    for (int ni = 0; ni < 4; ni++) acc[mi][ni] = f32x4{0.f, 0.f, 0.f, 0.f};

  for (int kk = 0; kk < D; kk += 32) {
    short8 af[4], bf[4];
#pragma unroll
    for (int mi = 0; mi < 4; mi++) af[mi] = *(const short8*)(a0 + (size_t)mi * 16 * D);
#pragma unroll
    for (int ni = 0; ni < 4; ni++) bf[ni] = *(const short8*)(b0 + (size_t)ni * 16 * D);
#pragma unroll
    for (int mi = 0; mi < 4; mi++)
#pragma unroll
      for (int ni = 0; ni < 4; ni++)
        acc[mi][ni] = MFMA_BF16(af[mi], bf[ni], acc[mi][ni]);
    a0 += 32;
    b0 += 32;
  }

#pragma unroll
  for (int mi = 0; mi < 4; mi++)
#pragma unroll
    for (int j = 0; j < 4; j++) {
      int grow = m0 + mi * 16 + c * 4 + j;
#pragma unroll
      for (int ni = 0; ni < 4; ni++) {
        int gcol = n0 + ni * 16 + r;
        out[(size_t)grow * D + gcol] = acc[mi][ni][j] + bias[gcol];
      }
    }
}

extern "C" void kernel_launch(void* const* d_in, const int* in_sizes, int n_in,
                              void* d_out, int out_size, void* d_ws, size_t ws_size,
                              hipStream_t stream) {
  const float* Q = (const float*)d_in[0];
  const float* K = (const float*)d_in[1];
  const float* V = (const float*)d_in[2];
  const float* Wq = (const float*)d_in[3];
  const float* Wk = (const float*)d_in[4];
  const float* Wv = (const float*)d_in[5];
  const float* Wo = (const float*)d_in[6];
  const float* bq = (const float*)d_in[7];
  const float* bk = (const float*)d_in[8];
  const float* bv = (const float*)d_in[9];
  const float* bo = (const float*)d_in[10];
  float* out = (float*)d_out;

  char* ws = (char*)d_ws;
  // layout (bytes):
  //   0        : wT  4 x 1024x1024 bf16            = 8,388,608
  //   8388608  : cos table 65536 f32               =   262,144
  //   8650752  : sin table 65536 f32               =   262,144
  //   8912896  : q   [B,H,L,hd] bf16               = 8,388,608
  //   17301504 : k   [B,H,L,hd] bf16               = 8,388,608
  //   25690112 : vT  [B,H,hd,L] bf16               = 8,388,608
  //   34078720 : O   [B,L,D]    bf16               = 8,388,608
  //   42467328 : xb  [3][4096][1024] bf16          = 25,165,824  (optional; total 67,633,152)
  u16* wT = (u16*)(ws);
  u16* woT = wT + (size_t)3 * 1024 * 1024;
  float* ct = (float*)(ws + 8388608);
  float* st = (float*)(ws + 8650752);
  u16* qbuf = (u16*)(ws + 8912896);
  u16* kbuf = (u16*)(ws + 17301504);
  u16* vbuf = (u16*)(ws + 25690112);
  u16* obuf = (u16*)(ws + 34078720);
  u16* xb = (u16*)(ws + 42467328);

  wt_trans_kernel<<<dim3(32, 32, 4), 256, 0, stream>>>(Wq, Wk, Wv, Wo, wT);
  rope_tab_kernel<<<dim3(256), 256, 0, stream>>>(ct, st);

  if (ws_size >= (size_t)67633152) {
    cvt_x_kernel<<<dim3(2048, 3), 256, 0, stream>>>(Q, K, V, xb);
    proj_gemm_kernel<true><<<dim3(768), 256, 0, stream>>>(Q, K, V, xb, wT, bq, bk, bv,
                                                          ct, st, qbuf, kbuf, vbuf);
  } else {
    proj_gemm_kernel<false><<<dim3(768), 256, 0, stream>>>(Q, K, V, nullptr, wT, bq, bk, bv,
                                                           ct, st, qbuf, kbuf, vbuf);
  }
  attn_kernel<<<dim3(1024), 256, 0, stream>>>(qbuf, kbuf, vbuf, obuf);
  oproj_gemm_kernel<<<dim3(256), 256, 0, stream>>>(obuf, woT, bo, out);
}

// Round 3
// 332.245 us; speedup vs baseline: 1.7624x; 1.2641x over previous
//
#include <hip/hip_runtime.h>

typedef __attribute__((ext_vector_type(8))) short short8;
typedef __attribute__((ext_vector_type(4))) float f32x4;
typedef unsigned short u16;
typedef unsigned int u32;

#define MFMA_BF16(a, b, c) __builtin_amdgcn_mfma_f32_16x16x32_bf16((a), (b), (c), 0, 0, 0)

constexpr int D = 1024;
constexpr int L = 2048;
constexpr int NHEAD = 16;
constexpr int HD = 64;

__device__ __forceinline__ u16 f2bf(float f) {
  unsigned u = __builtin_bit_cast(unsigned, f);
  u = (u + 0x7fffu + ((u >> 16) & 1u)) >> 16;
  return (u16)u;
}

__device__ __forceinline__ short8 cvt8(f32x4 lo, f32x4 hi) {
  short8 r;
  r[0] = (short)f2bf(lo[0]); r[1] = (short)f2bf(lo[1]);
  r[2] = (short)f2bf(lo[2]); r[3] = (short)f2bf(lo[3]);
  r[4] = (short)f2bf(hi[0]); r[5] = (short)f2bf(hi[1]);
  r[6] = (short)f2bf(hi[2]); r[7] = (short)f2bf(hi[3]);
  return r;
}

// async global->LDS, 16B per lane. dst must be wave-uniform; per-lane global src.
__device__ __forceinline__ void gload16(const u16* src, u16* dst) {
  __builtin_amdgcn_global_load_lds(
      (const __attribute__((address_space(1))) u32*)(src),
      (__attribute__((address_space(3))) u32*)(dst), 16, 0, 0);
}

// ---------- weight transpose + convert: W[k][n] f32 -> WT[n][k] bf16 ----------
__global__ __launch_bounds__(256) void wt_trans_kernel(const float* W0, const float* W1,
                                                       const float* W2, const float* W3,
                                                       u16* out) {
  const float* W = blockIdx.z == 0 ? W0 : blockIdx.z == 1 ? W1 : blockIdx.z == 2 ? W2 : W3;
  u16* o = out + (size_t)blockIdx.z * D * D;
  __shared__ float t[32][33];
  int x = threadIdx.x & 31, y = threadIdx.x >> 5;
  int k0 = blockIdx.x * 32, n0 = blockIdx.y * 32;
#pragma unroll
  for (int i = 0; i < 4; i++) {
    int ky = y * 4 + i;
    t[ky][x] = W[(size_t)(k0 + ky) * D + n0 + x];
  }
  __syncthreads();
#pragma unroll
  for (int i = 0; i < 4; i++) {
    int ny = y * 4 + i;
    o[(size_t)(n0 + ny) * D + k0 + x] = f2bf(t[x][ny]);
  }
}

// ---------- RoPE tables ----------
__global__ __launch_bounds__(256) void rope_tab_kernel(float* ct, float* st) {
  int t = blockIdx.x * 256 + threadIdx.x;  // L*32 = 65536
  int i = t & 31, pos = t >> 5;
  float invf = powf(10000.0f, -(float)i / 32.0f);
  float ang = (float)pos * invf;
  ct[t] = cosf(ang);
  st[t] = sinf(ang);
}

// ---------- convert X (Q,K,V inputs) f32 -> bf16 ----------
__global__ __launch_bounds__(256) void cvt_x_kernel(const float* Q, const float* K,
                                                    const float* V, u16* xb) {
  const float* src = blockIdx.y == 0 ? Q : blockIdx.y == 1 ? K : V;
  u16* dst = xb + (size_t)blockIdx.y * 4096 * D;
  int t = blockIdx.x * 256 + threadIdx.x;  // 524288 threads, 8 elems each
  const float* p = src + (size_t)t * 8;
  f32x4 lo = *(const f32x4*)p;
  f32x4 hi = *(const f32x4*)(p + 4);
  *(short8*)(dst + (size_t)t * 8) = cvt8(lo, hi);
}

// ======== staged GEMM core (128x128 tile, BK=32, LDS dbuf, gload_lds) ========
// LDS tile [128 rows][32 k] bf16, chunk = 8 elems; LDS[row][ch] = G[row][ch ^ ((row>>1)&3)]
// (for 64B row stride, f(row)=(row>>1)&3 gives per-phase bank-optimal reads)

// ---------- fused QKV projection GEMM + bias + RoPE epilogue ----------
__global__ __launch_bounds__(256, 3) void proj_gemm_staged(
    const u16* xb, const u16* wT,
    const float* bq, const float* bk, const float* bv,
    const float* ct, const float* st,
    u16* qo, u16* ko, u16* vT) {
  int i = blockIdx.x;  // 768 blocks, bijective XCD swizzle (768%8==0)
  int swz = (i & 7) * 96 + (i >> 3);
  int z = swz >> 8;
  int bx = swz & 7;
  int by = (swz >> 3) & 31;

  const u16* A = xb + (size_t)z * 4096 * D;
  const u16* W = wT + (size_t)z * D * D;
  const float* bias = z == 0 ? bq : z == 1 ? bk : bv;

  int w = threadIdx.x >> 6, lane = threadIdx.x & 63;
  int r = lane & 15, c = lane >> 4;
  int wr = w >> 1, wc = w & 1;
  int m0 = by * 128 + wr * 64;
  int n0 = bx * 128 + wc * 64;

  __shared__ __align__(16) u16 lsA[2][4096];
  __shared__ __align__(16) u16 lsB[2][4096];

  // staging sources: 2 chunks-of-64-lanes per wave per tensor
  const u16* aSrc[2];
  const u16* bSrc[2];
  int dstOff[2];
#pragma unroll
  for (int i2 = 0; i2 < 2; i2++) {
    int q0 = i2 * 256 + w * 64;
    int qq = q0 + lane;
    int t = qq >> 2;
    int gch = (qq & 3) ^ ((t >> 1) & 3);
    aSrc[i2] = A + (size_t)(by * 128 + t) * D + gch * 8;
    bSrc[i2] = W + (size_t)(bx * 128 + t) * D + gch * 8;
    dstOff[i2] = q0 * 8;
  }

  // LDS read offsets (elements)
  int aOff[4], bOff[4];
#pragma unroll
  for (int mi = 0; mi < 4; mi++) {
    int rowA = wr * 64 + mi * 16 + r;
    aOff[mi] = rowA * 32 + ((c ^ ((rowA >> 1) & 3)) << 3);
    int rowB = wc * 64 + mi * 16 + r;
    bOff[mi] = rowB * 32 + ((c ^ ((rowB >> 1) & 3)) << 3);
  }

  f32x4 acc[4][4];
#pragma unroll
  for (int mi = 0; mi < 4; mi++)
#pragma unroll
    for (int ni = 0; ni < 4; ni++) acc[mi][ni] = f32x4{0.f, 0.f, 0.f, 0.f};

  // prologue: stage kstep 0 into buf 0
#pragma unroll
  for (int i2 = 0; i2 < 2; i2++) {
    gload16(aSrc[i2], &lsA[0][dstOff[i2]]);
    gload16(bSrc[i2], &lsB[0][dstOff[i2]]);
  }

  auto compute = [&](const u16* pa, const u16* pb) {
    short8 af[4], bf[4];
#pragma unroll
    for (int mi = 0; mi < 4; mi++) af[mi] = *(const short8*)(pa + aOff[mi]);
#pragma unroll
    for (int ni = 0; ni < 4; ni++) bf[ni] = *(const short8*)(pb + bOff[ni]);
#pragma unroll
    for (int mi = 0; mi < 4; mi++)
#pragma unroll
      for (int ni = 0; ni < 4; ni++)
        acc[mi][ni] = MFMA_BF16(af[mi], bf[ni], acc[mi][ni]);
  };

  for (int kt = 0; kt < 31; kt++) {
    int cur = kt & 1;
    __syncthreads();  // vmcnt drain: stage of buf[cur] complete
#pragma unroll
    for (int i2 = 0; i2 < 2; i2++) {
      gload16(aSrc[i2] + (kt + 1) * 32, &lsA[cur ^ 1][dstOff[i2]]);
      gload16(bSrc[i2] + (kt + 1) * 32, &lsB[cur ^ 1][dstOff[i2]]);
    }
    compute(lsA[cur], lsB[cur]);
  }
  __syncthreads();
  compute(lsA[1], lsB[1]);

  int h = n0 >> 6;
#pragma unroll
  for (int mi = 0; mi < 4; mi++) {
#pragma unroll
    for (int j = 0; j < 4; j++) {
      int grow = m0 + mi * 16 + c * 4 + j;
      int b = grow >> 11, ll = grow & 2047;
      if (z < 2) {
        u16* o = (z == 0) ? qo : ko;
        size_t dst = ((size_t)(b * NHEAD + h) * L + ll) * HD;
#pragma unroll
        for (int ni = 0; ni < 2; ni++) {
          int d = ni * 16 + r;  // 0..31
          float x1 = acc[mi][ni][j] + bias[n0 + d];
          float x2 = acc[mi][ni + 2][j] + bias[n0 + 32 + d];
          float cs = ct[ll * 32 + d], sn = st[ll * 32 + d];
          o[dst + d]      = f2bf(x1 * cs - x2 * sn);
          o[dst + d + 32] = f2bf(x2 * cs + x1 * sn);
        }
      } else {
#pragma unroll
        for (int ni = 0; ni < 4; ni++) {
          int d = ni * 16 + r;
          float val = acc[mi][ni][j] + bias[n0 + d];
          vT[((size_t)(b * NHEAD + h) * HD + d) * L + ll] = f2bf(val);
        }
      }
    }
  }
}

// ---------- fallback projection (f32 A direct from global), if ws too small ----------
__global__ __launch_bounds__(256) void proj_gemm_f32(
    const float* Qf, const float* Kf, const float* Vf, const u16* wT,
    const float* bq, const float* bk, const float* bv,
    const float* ct, const float* st,
    u16* qo, u16* ko, u16* vT) {
  int i = blockIdx.x;
  int swz = (i & 7) * 96 + (i >> 3);
  int z = swz >> 8;
  int bx = swz & 7;
  int by = (swz >> 3) & 31;

  const u16* W = wT + (size_t)z * D * D;
  const float* bias = z == 0 ? bq : z == 1 ? bk : bv;

  int w = threadIdx.x >> 6, lane = threadIdx.x & 63;
  int r = lane & 15, c = lane >> 4;
  int wr = w >> 1, wc = w & 1;
  int m0 = by * 128 + wr * 64;
  int n0 = bx * 128 + wc * 64;

  const float* Af = z == 0 ? Qf : z == 1 ? Kf : Vf;
  const float* a0f = Af + (size_t)(m0 + r) * D + c * 8;
  const u16* b0 = W + (size_t)(n0 + r) * D + c * 8;

  f32x4 acc[4][4];
#pragma unroll
  for (int mi = 0; mi < 4; mi++)
#pragma unroll
    for (int ni = 0; ni < 4; ni++) acc[mi][ni] = f32x4{0.f, 0.f, 0.f, 0.f};

  for (int kk = 0; kk < D; kk += 32) {
    short8 af[4], bf[4];
#pragma unroll
    for (int mi = 0; mi < 4; mi++) {
      const float* ap = a0f + (size_t)mi * 16 * D;
      af[mi] = cvt8(*(const f32x4*)ap, *(const f32x4*)(ap + 4));
    }
#pragma unroll
    for (int ni = 0; ni < 4; ni++) bf[ni] = *(const short8*)(b0 + (size_t)ni * 16 * D);
#pragma unroll
    for (int mi = 0; mi < 4; mi++)
#pragma unroll
      for (int ni = 0; ni < 4; ni++)
        acc[mi][ni] = MFMA_BF16(af[mi], bf[ni], acc[mi][ni]);
    a0f += 32;
    b0 += 32;
  }

  int h = n0 >> 6;
#pragma unroll
  for (int mi = 0; mi < 4; mi++) {
#pragma unroll
    for (int j = 0; j < 4; j++) {
      int grow = m0 + mi * 16 + c * 4 + j;
      int b = grow >> 11, ll = grow & 2047;
      if (z < 2) {
        u16* o = (z == 0) ? qo : ko;
        size_t dst = ((size_t)(b * NHEAD + h) * L + ll) * HD;
#pragma unroll
        for (int ni = 0; ni < 2; ni++) {
          int d = ni * 16 + r;
          float x1 = acc[mi][ni][j] + bias[n0 + d];
          float x2 = acc[mi][ni + 2][j] + bias[n0 + 32 + d];
          float cs = ct[ll * 32 + d], sn = st[ll * 32 + d];
          o[dst + d]      = f2bf(x1 * cs - x2 * sn);
          o[dst + d + 32] = f2bf(x2 * cs + x1 * sn);
        }
      } else {
#pragma unroll
        for (int ni = 0; ni < 4; ni++) {
          int d = ni * 16 + r;
          float val = acc[mi][ni][j] + bias[n0 + d];
          vT[((size_t)(b * NHEAD + h) * HD + d) * L + ll] = f2bf(val);
        }
      }
    }
  }
}

// ---------- causal flash attention, KVBLK=64, LDS-staged K/V (2-phase dbuf) ----------
__global__ __launch_bounds__(256) void attn_kernel(const u16* qg, const u16* kg,
                                                   const u16* vg, u16* O) {
  int i = blockIdx.x;
  int sw = (i & 7) * 128 + (i >> 3);  // bijective, 1024%8==0
  int bh = sw >> 5;
  int qt = 31 - (sw & 31);  // heavy tiles first

  int w = threadIdx.x >> 6, lane = threadIdx.x & 63;
  int r = lane & 15, c = lane >> 4;
  int qb = qt * 64 + w * 16;

  const u16* qp = qg + ((size_t)bh * L + qb) * HD;
  const u16* kp = kg + (size_t)bh * L * HD;
  const u16* vp = vg + (size_t)bh * HD * L;

  __shared__ __align__(16) u16 kls[2][4096];
  __shared__ __align__(16) u16 vls[2][4096];
  __shared__ __align__(16) u16 plds[4][16][64];

  short8 aq0 = *(const short8*)(qp + r * HD + c * 8);
  short8 aq1 = *(const short8*)(qp + r * HD + 32 + c * 8);

  f32x4 o[4];
  float m[4], s[4];
#pragma unroll
  for (int n = 0; n < 4; n++) o[n] = f32x4{0.f, 0.f, 0.f, 0.f};
#pragma unroll
  for (int j = 0; j < 4; j++) { m[j] = -3.0e38f; s[j] = 0.f; }

  int nkt = qt + 1;

#pragma unroll
  for (int rd = 0; rd < 2; rd++) {
    int q0 = (rd * 4 + w) << 6;
    int qq = q0 + lane;
    int row = qq >> 3;
    int gch = (qq & 7) ^ (row & 7);
    gload16(kp + (size_t)row * HD + gch * 8, &kls[0][q0 * 8]);
    gload16(vp + (size_t)row * L + gch * 8, &vls[0][q0 * 8]);
  }

  for (int kt = 0; kt < nkt; kt++) {
    int cur = kt & 1;
    __syncthreads();
    if (kt + 1 < nkt) {
      int kb2 = (kt + 1) * 64;
      const u16* kp2 = kp + (size_t)kb2 * HD;
      const u16* vp2 = vp + kb2;
#pragma unroll
      for (int rd = 0; rd < 2; rd++) {
        int q0 = (rd * 4 + w) << 6;
        int qq = q0 + lane;
        int row = qq >> 3;
        int gch = (qq & 7) ^ (row & 7);
        gload16(kp2 + (size_t)row * HD + gch * 8, &kls[cur ^ 1][q0 * 8]);
        gload16(vp2 + (size_t)row * L + gch * 8, &vls[cur ^ 1][q0 * 8]);
      }
    }
    const u16* kb_ = kls[cur];
    const u16* vb_ = vls[cur];
    int kbase = kt * 64;

    f32x4 S[4];
#pragma unroll
    for (int ks = 0; ks < 4; ks++) {
      int row = ks * 16 + r;
      short8 kf0 = *(const short8*)(kb_ + row * 64 + ((c ^ (row & 7)) << 3));
      short8 kf1 = *(const short8*)(kb_ + row * 64 + (((4 + c) ^ (row & 7)) << 3));
      S[ks] = f32x4{0.f, 0.f, 0.f, 0.f};
      S[ks] = MFMA_BF16(aq0, kf0, S[ks]);
      S[ks] = MFMA_BF16(aq1, kf1, S[ks]);
    }

    bool edge = (kbase + 63) > qb;
#pragma unroll
    for (int j = 0; j < 4; j++) {
      float sv0 = S[0][j] * 0.125f, sv1 = S[1][j] * 0.125f;
      float sv2 = S[2][j] * 0.125f, sv3 = S[3][j] * 0.125f;
      if (edge) {
        int qrow = qb + c * 4 + j;
        if (kbase + r > qrow) sv0 = -3.0e38f;
        if (kbase + 16 + r > qrow) sv1 = -3.0e38f;
        if (kbase + 32 + r > qrow) sv2 = -3.0e38f;
        if (kbase + 48 + r > qrow) sv3 = -3.0e38f;
      }
      float mx = fmaxf(fmaxf(sv0, sv1), fmaxf(sv2, sv3));
      mx = fmaxf(mx, __shfl_xor(mx, 1));
      mx = fmaxf(mx, __shfl_xor(mx, 2));
      mx = fmaxf(mx, __shfl_xor(mx, 4));
      mx = fmaxf(mx, __shfl_xor(mx, 8));
      float mn = fmaxf(m[j], mx);
      float alpha = __expf(m[j] - mn);
      m[j] = mn;
      float p0 = __expf(sv0 - mn), p1 = __expf(sv1 - mn);
      float p2 = __expf(sv2 - mn), p3 = __expf(sv3 - mn);
      float rs = (p0 + p1) + (p2 + p3);
      rs += __shfl_xor(rs, 1);
      rs += __shfl_xor(rs, 2);
      rs += __shfl_xor(rs, 4);
      rs += __shfl_xor(rs, 8);
      s[j] = s[j] * alpha + rs;
      o[0][j] *= alpha;
      o[1][j] *= alpha;
      o[2][j] *= alpha;
      o[3][j] *= alpha;
      int prow = c * 4 + j, xr = (prow & 7) << 3;
      plds[w][prow][(r) ^ xr]      = f2bf(p0);
      plds[w][prow][(16 + r) ^ xr] = f2bf(p1);
      plds[w][prow][(32 + r) ^ xr] = f2bf(p2);
      plds[w][prow][(48 + r) ^ xr] = f2bf(p3);
    }

    int xrr = (r & 7) << 3;
    short8 pa0 = *(const short8*)&plds[w][r][(c * 8) ^ xrr];
    short8 pa1 = *(const short8*)&plds[w][r][(32 + c * 8) ^ xrr];
#pragma unroll
    for (int n = 0; n < 4; n++) {
      int row = n * 16 + r;
      short8 vf0 = *(const short8*)(vb_ + row * 64 + ((c ^ (row & 7)) << 3));
      short8 vf1 = *(const short8*)(vb_ + row * 64 + (((4 + c) ^ (row & 7)) << 3));
      o[n] = MFMA_BF16(pa0, vf0, o[n]);
      o[n] = MFMA_BF16(pa1, vf1, o[n]);
    }
  }

  int b = bh >> 4, h = bh & 15;
#pragma unroll
  for (int n = 0; n < 4; n++) {
#pragma unroll
    for (int j = 0; j < 4; j++) {
      int qrow = qb + c * 4 + j;
      float val = o[n][j] / s[j];
      O[((size_t)(b * L + qrow)) * D + h * HD + n * 16 + r] = f2bf(val);
    }
  }
}

// ---------- output projection (staged), f32 out + bias ----------
__global__ __launch_bounds__(256, 3) void oproj_gemm_staged(const u16* Ag, const u16* wT,
                                                            const float* bias, float* out) {
  int i = blockIdx.x;  // 256 blocks
  int swz = (i & 7) * 32 + (i >> 3);
  int bx = swz & 7, by = swz >> 3;

  int w = threadIdx.x >> 6, lane = threadIdx.x & 63;
  int r = lane & 15, c = lane >> 4;
  int wr = w >> 1, wc = w & 1;
  int m0 = by * 128 + wr * 64;
  int n0 = bx * 128 + wc * 64;

  __shared__ __align__(16) u16 lsA[2][4096];
  __shared__ __align__(16) u16 lsB[2][4096];

  const u16* aSrc[2];
  const u16* bSrc[2];
  int dstOff[2];
#pragma unroll
  for (int i2 = 0; i2 < 2; i2++) {
    int q0 = i2 * 256 + w * 64;
    int qq = q0 + lane;
    int t = qq >> 2;
    int gch = (qq & 3) ^ ((t >> 1) & 3);
    aSrc[i2] = Ag + (size_t)(by * 128 + t) * D + gch * 8;
    bSrc[i2] = wT + (size_t)(bx * 128 + t) * D + gch * 8;
    dstOff[i2] = q0 * 8;
  }

  int aOff[4], bOff[4];
#pragma unroll
  for (int mi = 0; mi < 4; mi++) {
    int rowA = wr * 64 + mi * 16 + r;
    aOff[mi] = rowA * 32 + ((c ^ ((rowA >> 1) & 3)) << 3);
    int rowB = wc * 64 + mi * 16 + r;
    bOff[mi] = rowB * 32 + ((c ^ ((rowB >> 1) & 3)) << 3);
  }

  f32x4 acc[4][4];
#pragma unroll
  for (int mi = 0; mi < 4; mi++)
#pragma unroll
    for (int ni = 0; ni < 4; ni++) acc[mi][ni] = f32x4{0.f, 0.f, 0.f, 0.f};

#pragma unroll
  for (int i2 = 0; i2 < 2; i2++) {
    gload16(aSrc[i2], &lsA[0][dstOff[i2]]);
    gload16(bSrc[i2], &lsB[0][dstOff[i2]]);
  }

  auto compute = [&](const u16* pa, const u16* pb) {
    short8 af[4], bf[4];
#pragma unroll
    for (int mi = 0; mi < 4; mi++) af[mi] = *(const short8*)(pa + aOff[mi]);
#pragma unroll
    for (int ni = 0; ni < 4; ni++) bf[ni] = *(const short8*)(pb + bOff[ni]);
#pragma unroll
    for (int mi = 0; mi < 4; mi++)
#pragma unroll
      for (int ni = 0; ni < 4; ni++)
        acc[mi][ni] = MFMA_BF16(af[mi], bf[ni], acc[mi][ni]);
  };

  for (int kt = 0; kt < 31; kt++) {
    int cur = kt & 1;
    __syncthreads();
#pragma unroll
    for (int i2 = 0; i2 < 2; i2++) {
      gload16(aSrc[i2] + (kt + 1) * 32, &lsA[cur ^ 1][dstOff[i2]]);
      gload16(bSrc[i2] + (kt + 1) * 32, &lsB[cur ^ 1][dstOff[i2]]);
    }
    compute(lsA[cur], lsB[cur]);
  }
  __syncthreads();
  compute(lsA[1], lsB[1]);

#pragma unroll
  for (int mi = 0; mi < 4; mi++)
#pragma unroll
    for (int j = 0; j < 4; j++) {
      int grow = m0 + mi * 16 + c * 4 + j;
#pragma unroll
      for (int ni = 0; ni < 4; ni++) {
        int gcol = n0 + ni * 16 + r;
        out[(size_t)grow * D + gcol] = acc[mi][ni][j] + bias[gcol];
      }
    }
}

extern "C" void kernel_launch(void* const* d_in, const int* in_sizes, int n_in,
                              void* d_out, int out_size, void* d_ws, size_t ws_size,
                              hipStream_t stream) {
  const float* Q = (const float*)d_in[0];
  const float* K = (const float*)d_in[1];
  const float* V = (const float*)d_in[2];
  const float* Wq = (const float*)d_in[3];
  const float* Wk = (const float*)d_in[4];
  const float* Wv = (const float*)d_in[5];
  const float* Wo = (const float*)d_in[6];
  const float* bq = (const float*)d_in[7];
  const float* bk = (const float*)d_in[8];
  const float* bv = (const float*)d_in[9];
  const float* bo = (const float*)d_in[10];
  float* out = (float*)d_out;

  char* ws = (char*)d_ws;
  // layout (bytes):
  //   0        : wT  4 x 1024x1024 bf16            = 8,388,608
  //   8388608  : cos table 65536 f32               =   262,144
  //   8650752  : sin table 65536 f32               =   262,144
  //   8912896  : q   [B,H,L,hd] bf16               = 8,388,608
  //   17301504 : k   [B,H,L,hd] bf16               = 8,388,608
  //   25690112 : vT  [B,H,hd,L] bf16               = 8,388,608
  //   34078720 : O   [B,L,D]    bf16               = 8,388,608
  //   42467328 : xb  [3][4096][1024] bf16          = 25,165,824  (total 67,633,152)
  u16* wT = (u16*)(ws);
  u16* woT = wT + (size_t)3 * 1024 * 1024;
  float* ct = (float*)(ws + 8388608);
  float* st = (float*)(ws + 8650752);
  u16* qbuf = (u16*)(ws + 8912896);
  u16* kbuf = (u16*)(ws + 17301504);
  u16* vbuf = (u16*)(ws + 25690112);
  u16* obuf = (u16*)(ws + 34078720);
  u16* xb = (u16*)(ws + 42467328);

  wt_trans_kernel<<<dim3(32, 32, 4), 256, 0, stream>>>(Wq, Wk, Wv, Wo, wT);
  rope_tab_kernel<<<dim3(256), 256, 0, stream>>>(ct, st);

  if (ws_size >= (size_t)67633152) {
    cvt_x_kernel<<<dim3(2048, 3), 256, 0, stream>>>(Q, K, V, xb);
    proj_gemm_staged<<<dim3(768), 256, 0, stream>>>(xb, wT, bq, bk, bv, ct, st,
                                                    qbuf, kbuf, vbuf);
  } else {
    proj_gemm_f32<<<dim3(768), 256, 0, stream>>>(Q, K, V, wT, bq, bk, bv, ct, st,
                                                 qbuf, kbuf, vbuf);
  }
  attn_kernel<<<dim3(1024), 256, 0, stream>>>(qbuf, kbuf, vbuf, obuf);
  oproj_gemm_staged<<<dim3(256), 256, 0, stream>>>(obuf, woT, bo, out);
}

// Round 4
// 329.495 us; speedup vs baseline: 1.7771x; 1.0083x over previous
//
#include <hip/hip_runtime.h>

typedef __attribute__((ext_vector_type(8))) short short8;
typedef __attribute__((ext_vector_type(4))) float f32x4;
typedef unsigned short u16;
typedef unsigned int u32;

#define MFMA_BF16(a, b, c) __builtin_amdgcn_mfma_f32_16x16x32_bf16((a), (b), (c), 0, 0, 0)

constexpr int D = 1024;
constexpr int L = 2048;
constexpr int NHEAD = 16;
constexpr int HD = 64;
// fold softmax scale (1/8) and log2(e) into q at projection time
constexpr float QLAMBDA = 0.125f * 1.44269504088896340736f;

__device__ __forceinline__ u16 f2bf(float f) {
  unsigned u = __builtin_bit_cast(unsigned, f);
  u = (u + 0x7fffu + ((u >> 16) & 1u)) >> 16;
  return (u16)u;
}

__device__ __forceinline__ short8 cvt8(f32x4 lo, f32x4 hi) {
  short8 r;
  r[0] = (short)f2bf(lo[0]); r[1] = (short)f2bf(lo[1]);
  r[2] = (short)f2bf(lo[2]); r[3] = (short)f2bf(lo[3]);
  r[4] = (short)f2bf(hi[0]); r[5] = (short)f2bf(hi[1]);
  r[6] = (short)f2bf(hi[2]); r[7] = (short)f2bf(hi[3]);
  return r;
}

// async global->LDS, 16B per lane. dst must be wave-uniform; per-lane global src.
__device__ __forceinline__ void gload16(const u16* src, u16* dst) {
  __builtin_amdgcn_global_load_lds(
      (const __attribute__((address_space(1))) u32*)(src),
      (__attribute__((address_space(3))) u32*)(dst), 16, 0, 0);
}

// ---------- weight transpose + convert: W[k][n] f32 -> WT[n][k] bf16 ----------
__global__ __launch_bounds__(256) void wt_trans_kernel(const float* W0, const float* W1,
                                                       const float* W2, const float* W3,
                                                       u16* out) {
  const float* W = blockIdx.z == 0 ? W0 : blockIdx.z == 1 ? W1 : blockIdx.z == 2 ? W2 : W3;
  u16* o = out + (size_t)blockIdx.z * D * D;
  __shared__ float t[32][33];
  int x = threadIdx.x & 31, y = threadIdx.x >> 5;
  int k0 = blockIdx.x * 32, n0 = blockIdx.y * 32;
#pragma unroll
  for (int i = 0; i < 4; i++) {
    int ky = y * 4 + i;
    t[ky][x] = W[(size_t)(k0 + ky) * D + n0 + x];
  }
  __syncthreads();
#pragma unroll
  for (int i = 0; i < 4; i++) {
    int ny = y * 4 + i;
    o[(size_t)(n0 + ny) * D + k0 + x] = f2bf(t[x][ny]);
  }
}

// ---------- RoPE tables ----------
__global__ __launch_bounds__(256) void rope_tab_kernel(float* ct, float* st) {
  int t = blockIdx.x * 256 + threadIdx.x;  // L*32 = 65536
  int i = t & 31, pos = t >> 5;
  float invf = powf(10000.0f, -(float)i / 32.0f);
  float ang = (float)pos * invf;
  ct[t] = cosf(ang);
  st[t] = sinf(ang);
}

// ---------- convert X (Q,K,V inputs) f32 -> bf16 ----------
__global__ __launch_bounds__(256) void cvt_x_kernel(const float* Q, const float* K,
                                                    const float* V, u16* xb) {
  const float* src = blockIdx.y == 0 ? Q : blockIdx.y == 1 ? K : V;
  u16* dst = xb + (size_t)blockIdx.y * 4096 * D;
  int t = blockIdx.x * 256 + threadIdx.x;  // 524288 threads, 8 elems each
  const float* p = src + (size_t)t * 8;
  f32x4 lo = *(const f32x4*)p;
  f32x4 hi = *(const f32x4*)(p + 4);
  *(short8*)(dst + (size_t)t * 8) = cvt8(lo, hi);
}

// ======== staged GEMM core (128x128 tile, BK=32, LDS dbuf, gload_lds) ========

// ---------- fused QKV projection GEMM + bias + RoPE epilogue ----------
__global__ __launch_bounds__(256, 3) void proj_gemm_staged(
    const u16* xb, const u16* wT,
    const float* bq, const float* bk, const float* bv,
    const float* ct, const float* st,
    u16* qo, u16* ko, u16* vT) {
  int i = blockIdx.x;  // 768 blocks, bijective XCD swizzle (768%8==0)
  int swz = (i & 7) * 96 + (i >> 3);
  int z = swz >> 8;
  int bx = swz & 7;
  int by = (swz >> 3) & 31;

  const u16* A = xb + (size_t)z * 4096 * D;
  const u16* W = wT + (size_t)z * D * D;
  const float* bias = z == 0 ? bq : z == 1 ? bk : bv;

  int w = threadIdx.x >> 6, lane = threadIdx.x & 63;
  int r = lane & 15, c = lane >> 4;
  int wr = w >> 1, wc = w & 1;
  int m0 = by * 128 + wr * 64;
  int n0 = bx * 128 + wc * 64;

  __shared__ __align__(16) u16 lsA[2][4096];
  __shared__ __align__(16) u16 lsB[2][4096];

  const u16* aSrc[2];
  const u16* bSrc[2];
  int dstOff[2];
#pragma unroll
  for (int i2 = 0; i2 < 2; i2++) {
    int q0 = i2 * 256 + w * 64;
    int qq = q0 + lane;
    int t = qq >> 2;
    int gch = (qq & 3) ^ ((t >> 1) & 3);
    aSrc[i2] = A + (size_t)(by * 128 + t) * D + gch * 8;
    bSrc[i2] = W + (size_t)(bx * 128 + t) * D + gch * 8;
    dstOff[i2] = q0 * 8;
  }

  int aOff[4], bOff[4];
#pragma unroll
  for (int mi = 0; mi < 4; mi++) {
    int rowA = wr * 64 + mi * 16 + r;
    aOff[mi] = rowA * 32 + ((c ^ ((rowA >> 1) & 3)) << 3);
    int rowB = wc * 64 + mi * 16 + r;
    bOff[mi] = rowB * 32 + ((c ^ ((rowB >> 1) & 3)) << 3);
  }

  f32x4 acc[4][4];
#pragma unroll
  for (int mi = 0; mi < 4; mi++)
#pragma unroll
    for (int ni = 0; ni < 4; ni++) acc[mi][ni] = f32x4{0.f, 0.f, 0.f, 0.f};

#pragma unroll
  for (int i2 = 0; i2 < 2; i2++) {
    gload16(aSrc[i2], &lsA[0][dstOff[i2]]);
    gload16(bSrc[i2], &lsB[0][dstOff[i2]]);
  }

  auto compute = [&](const u16* pa, const u16* pb) {
    short8 af[4], bf[4];
#pragma unroll
    for (int mi = 0; mi < 4; mi++) af[mi] = *(const short8*)(pa + aOff[mi]);
#pragma unroll
    for (int ni = 0; ni < 4; ni++) bf[ni] = *(const short8*)(pb + bOff[ni]);
#pragma unroll
    for (int mi = 0; mi < 4; mi++)
#pragma unroll
      for (int ni = 0; ni < 4; ni++)
        acc[mi][ni] = MFMA_BF16(af[mi], bf[ni], acc[mi][ni]);
  };

  for (int kt = 0; kt < 31; kt++) {
    int cur = kt & 1;
    __syncthreads();
#pragma unroll
    for (int i2 = 0; i2 < 2; i2++) {
      gload16(aSrc[i2] + (kt + 1) * 32, &lsA[cur ^ 1][dstOff[i2]]);
      gload16(bSrc[i2] + (kt + 1) * 32, &lsB[cur ^ 1][dstOff[i2]]);
    }
    compute(lsA[cur], lsB[cur]);
  }
  __syncthreads();
  compute(lsA[1], lsB[1]);

  int h = n0 >> 6;
#pragma unroll
  for (int mi = 0; mi < 4; mi++) {
#pragma unroll
    for (int j = 0; j < 4; j++) {
      int grow = m0 + mi * 16 + c * 4 + j;
      int b = grow >> 11, ll = grow & 2047;
      if (z < 2) {
        u16* o = (z == 0) ? qo : ko;
        float lam = (z == 0) ? QLAMBDA : 1.0f;
        size_t dst = ((size_t)(b * NHEAD + h) * L + ll) * HD;
#pragma unroll
        for (int ni = 0; ni < 2; ni++) {
          int d = ni * 16 + r;  // 0..31
          float x1 = acc[mi][ni][j] + bias[n0 + d];
          float x2 = acc[mi][ni + 2][j] + bias[n0 + 32 + d];
          float cs = ct[ll * 32 + d], sn = st[ll * 32 + d];
          o[dst + d]      = f2bf((x1 * cs - x2 * sn) * lam);
          o[dst + d + 32] = f2bf((x2 * cs + x1 * sn) * lam);
        }
      } else {
#pragma unroll
        for (int ni = 0; ni < 4; ni++) {
          int d = ni * 16 + r;
          float val = acc[mi][ni][j] + bias[n0 + d];
          vT[((size_t)(b * NHEAD + h) * HD + d) * L + ll] = f2bf(val);
        }
      }
    }
  }
}

// ---------- fallback projection (f32 A direct from global), if ws too small ----------
__global__ __launch_bounds__(256) void proj_gemm_f32(
    const float* Qf, const float* Kf, const float* Vf, const u16* wT,
    const float* bq, const float* bk, const float* bv,
    const float* ct, const float* st,
    u16* qo, u16* ko, u16* vT) {
  int i = blockIdx.x;
  int swz = (i & 7) * 96 + (i >> 3);
  int z = swz >> 8;
  int bx = swz & 7;
  int by = (swz >> 3) & 31;

  const u16* W = wT + (size_t)z * D * D;
  const float* bias = z == 0 ? bq : z == 1 ? bk : bv;

  int w = threadIdx.x >> 6, lane = threadIdx.x & 63;
  int r = lane & 15, c = lane >> 4;
  int wr = w >> 1, wc = w & 1;
  int m0 = by * 128 + wr * 64;
  int n0 = bx * 128 + wc * 64;

  const float* Af = z == 0 ? Qf : z == 1 ? Kf : Vf;
  const float* a0f = Af + (size_t)(m0 + r) * D + c * 8;
  const u16* b0 = W + (size_t)(n0 + r) * D + c * 8;

  f32x4 acc[4][4];
#pragma unroll
  for (int mi = 0; mi < 4; mi++)
#pragma unroll
    for (int ni = 0; ni < 4; ni++) acc[mi][ni] = f32x4{0.f, 0.f, 0.f, 0.f};

  for (int kk = 0; kk < D; kk += 32) {
    short8 af[4], bf[4];
#pragma unroll
    for (int mi = 0; mi < 4; mi++) {
      const float* ap = a0f + (size_t)mi * 16 * D;
      af[mi] = cvt8(*(const f32x4*)ap, *(const f32x4*)(ap + 4));
    }
#pragma unroll
    for (int ni = 0; ni < 4; ni++) bf[ni] = *(const short8*)(b0 + (size_t)ni * 16 * D);
#pragma unroll
    for (int mi = 0; mi < 4; mi++)
#pragma unroll
      for (int ni = 0; ni < 4; ni++)
        acc[mi][ni] = MFMA_BF16(af[mi], bf[ni], acc[mi][ni]);
    a0f += 32;
    b0 += 32;
  }

  int h = n0 >> 6;
#pragma unroll
  for (int mi = 0; mi < 4; mi++) {
#pragma unroll
    for (int j = 0; j < 4; j++) {
      int grow = m0 + mi * 16 + c * 4 + j;
      int b = grow >> 11, ll = grow & 2047;
      if (z < 2) {
        u16* o = (z == 0) ? qo : ko;
        float lam = (z == 0) ? QLAMBDA : 1.0f;
        size_t dst = ((size_t)(b * NHEAD + h) * L + ll) * HD;
#pragma unroll
        for (int ni = 0; ni < 2; ni++) {
          int d = ni * 16 + r;
          float x1 = acc[mi][ni][j] + bias[n0 + d];
          float x2 = acc[mi][ni + 2][j] + bias[n0 + 32 + d];
          float cs = ct[ll * 32 + d], sn = st[ll * 32 + d];
          o[dst + d]      = f2bf((x1 * cs - x2 * sn) * lam);
          o[dst + d + 32] = f2bf((x2 * cs + x1 * sn) * lam);
        }
      } else {
#pragma unroll
        for (int ni = 0; ni < 4; ni++) {
          int d = ni * 16 + r;
          float val = acc[mi][ni][j] + bias[n0 + d];
          vT[((size_t)(b * NHEAD + h) * HD + d) * L + ll] = f2bf(val);
        }
      }
    }
  }
}

// ---------- causal flash attention, KVBLK=64, LDS-staged K/V (2-phase dbuf) ----------
// Per-XCD dispatch order balanced for breadth-first placement: CU slot c gets
// qt = {31-c, c, 31-c, c} across 4 heads -> 66 K-tiles per CU, uniform.
__global__ __launch_bounds__(256) void attn_kernel(const u16* qg, const u16* kg,
                                                   const u16* vg, u16* O) {
  int i = blockIdx.x;
  int xcd = i & 7, j = i >> 3;   // j in [0,128) within XCD
  int rnd = j >> 5, cslot = j & 31;
  int bh = xcd * 4 + rnd;
  int qt = (rnd & 1) ? cslot : 31 - cslot;

  int w = threadIdx.x >> 6, lane = threadIdx.x & 63;
  int r = lane & 15, c = lane >> 4;
  int qb = qt * 64 + w * 16;

  const u16* qp = qg + ((size_t)bh * L + qb) * HD;
  const u16* kp = kg + (size_t)bh * L * HD;
  const u16* vp = vg + (size_t)bh * HD * L;

  __shared__ __align__(16) u16 kls[2][4096];
  __shared__ __align__(16) u16 vls[2][4096];
  __shared__ __align__(16) u16 plds[4][16][64];

  short8 aq0 = *(const short8*)(qp + r * HD + c * 8);
  short8 aq1 = *(const short8*)(qp + r * HD + 32 + c * 8);

  f32x4 o[4];
  float m[4], s[4];
#pragma unroll
  for (int n = 0; n < 4; n++) o[n] = f32x4{0.f, 0.f, 0.f, 0.f};
#pragma unroll
  for (int j4 = 0; j4 < 4; j4++) { m[j4] = -3.0e38f; s[j4] = 0.f; }

  int nkt = qt + 1;

#pragma unroll
  for (int rd = 0; rd < 2; rd++) {
    int q0 = (rd * 4 + w) << 6;
    int qq = q0 + lane;
    int row = qq >> 3;
    int gch = (qq & 7) ^ (row & 7);
    gload16(kp + (size_t)row * HD + gch * 8, &kls[0][q0 * 8]);
    gload16(vp + (size_t)row * L + gch * 8, &vls[0][q0 * 8]);
  }

  for (int kt = 0; kt < nkt; kt++) {
    int cur = kt & 1;
    __syncthreads();
    if (kt + 1 < nkt) {
      int kb2 = (kt + 1) * 64;
      const u16* kp2 = kp + (size_t)kb2 * HD;
      const u16* vp2 = vp + kb2;
#pragma unroll
      for (int rd = 0; rd < 2; rd++) {
        int q0 = (rd * 4 + w) << 6;
        int qq = q0 + lane;
        int row = qq >> 3;
        int gch = (qq & 7) ^ (row & 7);
        gload16(kp2 + (size_t)row * HD + gch * 8, &kls[cur ^ 1][q0 * 8]);
        gload16(vp2 + (size_t)row * L + gch * 8, &vls[cur ^ 1][q0 * 8]);
      }
    }
    const u16* kb_ = kls[cur];
    const u16* vb_ = vls[cur];
    int kbase = kt * 64;

    f32x4 S[4];
#pragma unroll
    for (int ks = 0; ks < 4; ks++) {
      int row = ks * 16 + r;
      short8 kf0 = *(const short8*)(kb_ + row * 64 + ((c ^ (row & 7)) << 3));
      short8 kf1 = *(const short8*)(kb_ + row * 64 + (((4 + c) ^ (row & 7)) << 3));
      S[ks] = f32x4{0.f, 0.f, 0.f, 0.f};
      S[ks] = MFMA_BF16(aq0, kf0, S[ks]);
      S[ks] = MFMA_BF16(aq1, kf1, S[ks]);
    }

    bool edge = (kbase + 63) > qb;
#pragma unroll
    for (int j4 = 0; j4 < 4; j4++) {
      float sv0 = S[0][j4], sv1 = S[1][j4], sv2 = S[2][j4], sv3 = S[3][j4];
      if (edge) {
        int qrow = qb + c * 4 + j4;
        if (kbase + r > qrow) sv0 = -3.0e38f;
        if (kbase + 16 + r > qrow) sv1 = -3.0e38f;
        if (kbase + 32 + r > qrow) sv2 = -3.0e38f;
        if (kbase + 48 + r > qrow) sv3 = -3.0e38f;
      }
      float mx = fmaxf(fmaxf(sv0, sv1), fmaxf(sv2, sv3));
      mx = fmaxf(mx, __shfl_xor(mx, 1));
      mx = fmaxf(mx, __shfl_xor(mx, 2));
      mx = fmaxf(mx, __shfl_xor(mx, 4));
      mx = fmaxf(mx, __shfl_xor(mx, 8));
      // defer-max (T13): only rescale when max grew beyond threshold (exp2 domain)
      if (__any(mx > m[j4] + 8.0f)) {
        float mn = fmaxf(m[j4], mx);
        float al = exp2f(m[j4] - mn);
        m[j4] = mn;
        s[j4] *= al;
        o[0][j4] *= al;
        o[1][j4] *= al;
        o[2][j4] *= al;
        o[3][j4] *= al;
      }
      float p0 = exp2f(sv0 - m[j4]), p1 = exp2f(sv1 - m[j4]);
      float p2 = exp2f(sv2 - m[j4]), p3 = exp2f(sv3 - m[j4]);
      float rs = (p0 + p1) + (p2 + p3);
      rs += __shfl_xor(rs, 1);
      rs += __shfl_xor(rs, 2);
      rs += __shfl_xor(rs, 4);
      rs += __shfl_xor(rs, 8);
      s[j4] += rs;
      int prow = c * 4 + j4, xr = (prow & 7) << 3;
      plds[w][prow][(r) ^ xr]      = f2bf(p0);
      plds[w][prow][(16 + r) ^ xr] = f2bf(p1);
      plds[w][prow][(32 + r) ^ xr] = f2bf(p2);
      plds[w][prow][(48 + r) ^ xr] = f2bf(p3);
    }

    int xrr = (r & 7) << 3;
    short8 pa0 = *(const short8*)&plds[w][r][(c * 8) ^ xrr];
    short8 pa1 = *(const short8*)&plds[w][r][(32 + c * 8) ^ xrr];
#pragma unroll
    for (int n = 0; n < 4; n++) {
      int row = n * 16 + r;
      short8 vf0 = *(const short8*)(vb_ + row * 64 + ((c ^ (row & 7)) << 3));
      short8 vf1 = *(const short8*)(vb_ + row * 64 + (((4 + c) ^ (row & 7)) << 3));
      o[n] = MFMA_BF16(pa0, vf0, o[n]);
      o[n] = MFMA_BF16(pa1, vf1, o[n]);
    }
  }

  int b = bh >> 4, h = bh & 15;
#pragma unroll
  for (int n = 0; n < 4; n++) {
#pragma unroll
    for (int j4 = 0; j4 < 4; j4++) {
      int qrow = qb + c * 4 + j4;
      float val = o[n][j4] / s[j4];
      O[((size_t)(b * L + qrow)) * D + h * HD + n * 16 + r] = f2bf(val);
    }
  }
}

// ---------- output projection (staged), f32 out + bias ----------
__global__ __launch_bounds__(256, 3) void oproj_gemm_staged(const u16* Ag, const u16* wT,
                                                            const float* bias, float* out) {
  int i = blockIdx.x;  // 256 blocks
  int swz = (i & 7) * 32 + (i >> 3);
  int bx = swz & 7, by = swz >> 3;

  int w = threadIdx.x >> 6, lane = threadIdx.x & 63;
  int r = lane & 15, c = lane >> 4;
  int wr = w >> 1, wc = w & 1;
  int m0 = by * 128 + wr * 64;
  int n0 = bx * 128 + wc * 64;

  __shared__ __align__(16) u16 lsA[2][4096];
  __shared__ __align__(16) u16 lsB[2][4096];

  const u16* aSrc[2];
  const u16* bSrc[2];
  int dstOff[2];
#pragma unroll
  for (int i2 = 0; i2 < 2; i2++) {
    int q0 = i2 * 256 + w * 64;
    int qq = q0 + lane;
    int t = qq >> 2;
    int gch = (qq & 3) ^ ((t >> 1) & 3);
    aSrc[i2] = Ag + (size_t)(by * 128 + t) * D + gch * 8;
    bSrc[i2] = wT + (size_t)(bx * 128 + t) * D + gch * 8;
    dstOff[i2] = q0 * 8;
  }

  int aOff[4], bOff[4];
#pragma unroll
  for (int mi = 0; mi < 4; mi++) {
    int rowA = wr * 64 + mi * 16 + r;
    aOff[mi] = rowA * 32 + ((c ^ ((rowA >> 1) & 3)) << 3);
    int rowB = wc * 64 + mi * 16 + r;
    bOff[mi] = rowB * 32 + ((c ^ ((rowB >> 1) & 3)) << 3);
  }

  f32x4 acc[4][4];
#pragma unroll
  for (int mi = 0; mi < 4; mi++)
#pragma unroll
    for (int ni = 0; ni < 4; ni++) acc[mi][ni] = f32x4{0.f, 0.f, 0.f, 0.f};

#pragma unroll
  for (int i2 = 0; i2 < 2; i2++) {
    gload16(aSrc[i2], &lsA[0][dstOff[i2]]);
    gload16(bSrc[i2], &lsB[0][dstOff[i2]]);
  }

  auto compute = [&](const u16* pa, const u16* pb) {
    short8 af[4], bf[4];
#pragma unroll
    for (int mi = 0; mi < 4; mi++) af[mi] = *(const short8*)(pa + aOff[mi]);
#pragma unroll
    for (int ni = 0; ni < 4; ni++) bf[ni] = *(const short8*)(pb + bOff[ni]);
#pragma unroll
    for (int mi = 0; mi < 4; mi++)
#pragma unroll
      for (int ni = 0; ni < 4; ni++)
        acc[mi][ni] = MFMA_BF16(af[mi], bf[ni], acc[mi][ni]);
  };

  for (int kt = 0; kt < 31; kt++) {
    int cur = kt & 1;
    __syncthreads();
#pragma unroll
    for (int i2 = 0; i2 < 2; i2++) {
      gload16(aSrc[i2] + (kt + 1) * 32, &lsA[cur ^ 1][dstOff[i2]]);
      gload16(bSrc[i2] + (kt + 1) * 32, &lsB[cur ^ 1][dstOff[i2]]);
    }
    compute(lsA[cur], lsB[cur]);
  }
  __syncthreads();
  compute(lsA[1], lsB[1]);

#pragma unroll
  for (int mi = 0; mi < 4; mi++)
#pragma unroll
    for (int j = 0; j < 4; j++) {
      int grow = m0 + mi * 16 + c * 4 + j;
#pragma unroll
      for (int ni = 0; ni < 4; ni++) {
        int gcol = n0 + ni * 16 + r;
        out[(size_t)grow * D + gcol] = acc[mi][ni][j] + bias[gcol];
      }
    }
}

extern "C" void kernel_launch(void* const* d_in, const int* in_sizes, int n_in,
                              void* d_out, int out_size, void* d_ws, size_t ws_size,
                              hipStream_t stream) {
  const float* Q = (const float*)d_in[0];
  const float* K = (const float*)d_in[1];
  const float* V = (const float*)d_in[2];
  const float* Wq = (const float*)d_in[3];
  const float* Wk = (const float*)d_in[4];
  const float* Wv = (const float*)d_in[5];
  const float* Wo = (const float*)d_in[6];
  const float* bq = (const float*)d_in[7];
  const float* bk = (const float*)d_in[8];
  const float* bv = (const float*)d_in[9];
  const float* bo = (const float*)d_in[10];
  float* out = (float*)d_out;

  char* ws = (char*)d_ws;
  u16* wT = (u16*)(ws);
  u16* woT = wT + (size_t)3 * 1024 * 1024;
  float* ct = (float*)(ws + 8388608);
  float* st = (float*)(ws + 8650752);
  u16* qbuf = (u16*)(ws + 8912896);
  u16* kbuf = (u16*)(ws + 17301504);
  u16* vbuf = (u16*)(ws + 25690112);
  u16* obuf = (u16*)(ws + 34078720);
  u16* xb = (u16*)(ws + 42467328);

  wt_trans_kernel<<<dim3(32, 32, 4), 256, 0, stream>>>(Wq, Wk, Wv, Wo, wT);
  rope_tab_kernel<<<dim3(256), 256, 0, stream>>>(ct, st);

  if (ws_size >= (size_t)67633152) {
    cvt_x_kernel<<<dim3(2048, 3), 256, 0, stream>>>(Q, K, V, xb);
    proj_gemm_staged<<<dim3(768), 256, 0, stream>>>(xb, wT, bq, bk, bv, ct, st,
                                                    qbuf, kbuf, vbuf);
  } else {
    proj_gemm_f32<<<dim3(768), 256, 0, stream>>>(Q, K, V, wT, bq, bk, bv, ct, st,
                                                 qbuf, kbuf, vbuf);
  }
  attn_kernel<<<dim3(1024), 256, 0, stream>>>(qbuf, kbuf, vbuf, obuf);
  oproj_gemm_staged<<<dim3(256), 256, 0, stream>>>(obuf, woT, bo, out);
}